// Round 5
// baseline (481.905 us; speedup 1.0000x reference)
//
#include <hip/hip_runtime.h>

// ---------------------------------------------------------------------------
// qp = q@Wq.T ; kp = qp@Wk.T (quirk) ; vp = v@Wv.T
// att = softmax(causal(q k^T * sqrt(D))) ; y = att v ; out = y@Wp.T + bp
// Round-5: kp = q@(Wk@Wq)^T  ->  qp,kp fused into ONE split GEMM (N=2048,
// 1024 blocks = 4/CU exact). Split GEMMs BK=32/32KB LDS, per-j b-frags,
// __launch_bounds__(256,4) (m97 occupancy, not m132's 2-block trap).
// Plain GEMMs 128x64 tiles (1024 blocks). Score path split bf16 hi/lo
// interleaved, 3-term MFMA (validated: absmax 0.0078 vs 0.0403 threshold).
//
// ws (u16, 6*NE = 96MB exactly):
//   wq_i[0,2WE) wqk_i[2WE,4WE) wk_i[4WE,6WE) wv_b[6WE,7WE) wp_b[7WE,8WE)
//   vb[8WE,8WE+NE) (ybf after vp-GEMM)  qp_i[+2NE)  kp_i[+2NE)
//   (wqT_i aliases kp_i's first 2WE: dead before kp written)
// d_out scratch (2NE u16): qs_i [0,2NE) until merged GEMM; vpT [0,NE) after.
// ---------------------------------------------------------------------------

typedef unsigned short u16;
typedef unsigned int   u32;
typedef __attribute__((ext_vector_type(8))) __bf16 bf16x8;
typedef __attribute__((ext_vector_type(8))) u16    u16x8;
typedef __attribute__((ext_vector_type(4))) u16    u16x4;
typedef __attribute__((ext_vector_type(4))) float  f32x4;
typedef __attribute__((ext_vector_type(4))) int    i32x4;

#define DEV static __device__ __forceinline__

DEV u16 f2bf(float x){ union{float f;u32 u;}v; v.f=x; u32 r=v.u+0x7fffu+((v.u>>16)&1u); return (u16)(r>>16); }
DEV float bf2f(u16 b){ union{u32 u;float f;}v; v.u=((u32)b)<<16; return v.f; }
DEV f32x4 zero4(){ f32x4 z={0.f,0.f,0.f,0.f}; return z; }
DEV f32x4 mfma16(bf16x8 a, bf16x8 b, f32x4 c){ return __builtin_amdgcn_mfma_f32_16x16x32_bf16(a,b,c,0,0,0); }
DEV void gld16(const u16* g, u16* l){
  __builtin_amdgcn_global_load_lds((const __attribute__((address_space(1))) u32*)g,
                                   (__attribute__((address_space(3))) u32*)l, 16, 0, 0);
}
DEV u32 pkbf(float a, float b){
  union{float f;u32 u;}x,y; x.f=a; y.f=b;
  return __builtin_amdgcn_perm(y.u+0x8000u, x.u+0x8000u, 0x07060302u);
}

constexpr int B_=4, T_=2048, E_=1024;
constexpr int M_=B_*T_;                  // 8192
constexpr float L2E8 = 11.5415603f;      // 8/ln2

// ---------------------------------------------------------------------------
__global__ __launch_bounds__(256)
void cvt_a(const float* __restrict__ q, const float* __restrict__ v,
           u16* __restrict__ qi, u16* __restrict__ vb)
{
  const int j=blockIdx.y;
  const size_t e=((size_t)blockIdx.x*256+threadIdx.x)*8;
  const float* s=(j==0)?q:v;
  f32x4 x0=*reinterpret_cast<const f32x4*>(s+e);
  f32x4 x1=*reinterpret_cast<const f32x4*>(s+e+4);
  u16x8 h,l;
#pragma unroll
  for(int t=0;t<4;t++){
    u16 hh=f2bf(x0[t]); h[t]=hh; l[t]=f2bf(x0[t]-bf2f(hh));
    u16 h2=f2bf(x1[t]); h[t+4]=h2; l[t+4]=f2bf(x1[t]-bf2f(h2));
  }
  if(j==0){
    const size_t row=e>>10, k=e&1023;
    u16* d=qi + row*2048 + (k>>3)*16;
    *reinterpret_cast<u16x8*>(d)=h;
    *reinterpret_cast<u16x8*>(d+8)=l;
  } else {
    *reinterpret_cast<u16x8*>(vb+e)=h;
  }
}

// 4 weights: Wq->split_i, Wk->split_i, Wv->plain, Wp->plain
__global__ __launch_bounds__(256)
void cvt_w(const float* __restrict__ Wq, const float* __restrict__ Wk,
           const float* __restrict__ Wv, const float* __restrict__ Wp,
           u16* __restrict__ wqi, u16* __restrict__ wki,
           u16* __restrict__ wvb, u16* __restrict__ wpb)
{
  const int j=blockIdx.y;
  const size_t e=((size_t)blockIdx.x*256+threadIdx.x)*8;
  const float* s=(j==0)?Wq:(j==1)?Wk:(j==2)?Wv:Wp;
  f32x4 x0=*reinterpret_cast<const f32x4*>(s+e);
  f32x4 x1=*reinterpret_cast<const f32x4*>(s+e+4);
  u16x8 h,l;
#pragma unroll
  for(int t=0;t<4;t++){
    u16 hh=f2bf(x0[t]); h[t]=hh; l[t]=f2bf(x0[t]-bf2f(hh));
    u16 h2=f2bf(x1[t]); h[t+4]=h2; l[t+4]=f2bf(x1[t]-bf2f(h2));
  }
  if(j>=2){ *reinterpret_cast<u16x8*>(((j==2)?wvb:wpb)+e)=h; return; }
  u16* base=(j==0)?wqi:wki;
  const size_t row=e>>10, k=e&1023;
  u16* d=base + row*2048 + (k>>3)*16;
  *reinterpret_cast<u16x8*>(d)=h;
  *reinterpret_cast<u16x8*>(d+8)=l;
}

// transpose-convert: oT (split-interleaved) row j = column j of W
__global__ __launch_bounds__(256)
void cvt_t(const float* __restrict__ W, u16* __restrict__ oT)
{
  __shared__ float t[64][65];
  const int r0=blockIdx.y*64, c0=blockIdx.x*64, tid=threadIdx.x;
#pragma unroll
  for(int p=0;p<4;p++){
    const int r=p*16+(tid>>4), c=(tid&15)*4;
    f32x4 v=*reinterpret_cast<const f32x4*>(W+(size_t)(r0+r)*1024 + c0+c);
#pragma unroll
    for(int g=0;g<4;g++) t[r][c+g]=v[g];
  }
  __syncthreads();
  const int cc=tid>>2, ks=(tid&3)*16;
#pragma unroll
  for(int g=0;g<2;g++){
    u16x8 h,l;
#pragma unroll
    for(int u=0;u<8;u++){
      float x=t[ks+g*8+u][cc];
      u16 hh=f2bf(x); h[u]=hh; l[u]=f2bf(x-bf2f(hh));
    }
    u16* d=oT + (size_t)(c0+cc)*2048 + (size_t)((r0+ks)>>3)*16 + g*16;
    *reinterpret_cast<u16x8*>(d)=h;
    *reinterpret_cast<u16x8*>(d+8)=l;
  }
}

// ---------------------------------------------------------------------------
// GEMM C[M',N'] = A[M',K] @ B[N',K]^T, K=1024. Block: 128 x NT, 4 waves as
// 2x2 of 64 x NT/2. gld16 staging with XOR chunk swizzle phys=j^(row&7).
// SPLIT: interleaved hi/lo rows (2048 u16), BK=32, 3-term MFMA, b-frag per j.
// PLAIN: BK=64. OMODE: 0 split-i out (col>=1024 -> Ob2) ; 1 bf16 ldc ; 2 f32+bias.
// ---------------------------------------------------------------------------
template<int SPLIT,int NT,int OMODE>
__global__ __launch_bounds__(256,4)
void gemm(const u16* __restrict__ Ag, const u16* __restrict__ Bg,
          const float* __restrict__ bias,
          u16* __restrict__ Ob, u16* __restrict__ Ob2,
          float* __restrict__ Of, int ldc)
{
  constexpr int JN=NT/32;                // j-tiles per wave
  __shared__ u16 sA[128*64];
  __shared__ u16 sB[NT*64];

  const int tid=threadIdx.x, wave=tid>>6, lane=tid&63;
  const int quad=lane>>4, l16=lane&15, sw=l16&7;
  const int wm=(wave>>1)*64, wn=(wave&1)*(NT/2);
  const int n0=blockIdx.x*NT, m0=blockIdx.y*128;
  constexpr int KSTEP=SPLIT?32:64;

  f32x4 acc[4][JN];
#pragma unroll
  for(int i=0;i<4;i++)
#pragma unroll
    for(int j=0;j<JN;j++) acc[i][j]=zero4();

  for(int k0=0;k0<E_;k0+=KSTEP){
    // A tile: 128 rows x 8 chunks
#pragma unroll
    for(int it=0;it<4;it++){
      const int c=it*256+tid, row=c>>3, j=(c&7)^(row&7);
      const u16* ga = SPLIT ? Ag + (size_t)(m0+row)*2048 + (size_t)k0*2 + j*8
                            : Ag + (size_t)(m0+row)*1024 + k0 + j*8;
      gld16(ga, &sA[(it*256+wave*64)*8]);
    }
    // B tile: NT rows x 8 chunks
#pragma unroll
    for(int it=0;it<NT/32;it++){
      const int c=it*256+tid, row=c>>3, j=(c&7)^(row&7);
      const u16* gb = SPLIT ? Bg + (size_t)(n0+row)*2048 + (size_t)k0*2 + j*8
                            : Bg + (size_t)(n0+row)*1024 + k0 + j*8;
      gld16(gb, &sB[(it*256+wave*64)*8]);
    }
    __syncthreads();

    if(SPLIT){
      bf16x8 ahh[4],ahl[4];
#pragma unroll
      for(int i=0;i<4;i++){
        const u16* pa=&sA[(wm+i*16+l16)*64];
        ahh[i]=*reinterpret_cast<const bf16x8*>(&pa[((2*quad  )^sw)*8]);
        ahl[i]=*reinterpret_cast<const bf16x8*>(&pa[((2*quad+1)^sw)*8]);
      }
#pragma unroll
      for(int j=0;j<JN;j++){
        const u16* pb=&sB[(wn+j*16+l16)*64];
        bf16x8 bhh=*reinterpret_cast<const bf16x8*>(&pb[((2*quad  )^sw)*8]);
        bf16x8 bhl=*reinterpret_cast<const bf16x8*>(&pb[((2*quad+1)^sw)*8]);
#pragma unroll
        for(int i=0;i<4;i++){
          acc[i][j]=mfma16(ahh[i],bhh,acc[i][j]);
          acc[i][j]=mfma16(ahh[i],bhl,acc[i][j]);
          acc[i][j]=mfma16(ahl[i],bhh,acc[i][j]);
        }
      }
    } else {
#pragma unroll
      for(int kk=0;kk<2;kk++){
        bf16x8 a[4];
#pragma unroll
        for(int i=0;i<4;i++)
          a[i]=*reinterpret_cast<const bf16x8*>(&sA[(wm+i*16+l16)*64 + (((kk*4+quad)^sw)*8)]);
#pragma unroll
        for(int j=0;j<JN;j++){
          bf16x8 b=*reinterpret_cast<const bf16x8*>(&sB[(wn+j*16+l16)*64 + (((kk*4+quad)^sw)*8)]);
#pragma unroll
          for(int i=0;i<4;i++)
            acc[i][j]=mfma16(a[i],b,acc[i][j]);
        }
      }
    }
    __syncthreads();
  }

  // epilogue: D row=quad*4+r, col=l16 (verified)
#pragma unroll
  for(int i=0;i<4;i++)
#pragma unroll
    for(int j=0;j<JN;j++){
      const int col=n0+wn+j*16+l16;
#pragma unroll
      for(int r=0;r<4;r++){
        const int row=m0+wm+i*16+quad*4+r;
        float v=acc[i][j][r];
        if(OMODE==2)      Of[(size_t)row*ldc+col]=v+bias[col];
        else if(OMODE==1) Ob[(size_t)row*ldc+col]=f2bf(v);
        else {
          u16* base=(col<1024)?Ob:Ob2;
          const int c1=col&1023;
          const size_t ba=(size_t)row*2048 + (size_t)(c1>>3)*16 + (c1&7);
          u16 hh=f2bf(v);
          base[ba]=hh; base[ba+8]=f2bf(v-bf2f(hh));
        }
      }
    }
}

// ---------------------------------------------------------------------------
// Flash attention, S^T orientation (r2-r4 verified). K (hi/lo interleaved)
// and V^T staged via gld16 + XOR swizzle. Mask hoisted out of non-diagonal
// tiles. exp2-fused softmax; l cross-quad reduction deferred to epilogue.
// ---------------------------------------------------------------------------
__global__ __launch_bounds__(256)
void attn(const u16* __restrict__ qpi, const u16* __restrict__ kpi,
          const u16* __restrict__ vpT, u16* __restrict__ yout)
{
  __shared__ u16 sK [64*128];
  __shared__ u16 sVT[64*64];

  const int tid=threadIdx.x, wave=tid>>6, lane=tid&63;
  const int quad=lane>>4, l16=lane&15, sw=l16&7;
  const int qt=(int)(gridDim.x-1-blockIdx.x)>>6;
  const int bh=blockIdx.x&63;
  const int b=bh>>4, h=bh&15;
  const int qr0=qt*128+wave*32;

  bf16x8 qfh[2][2], qfl[2][2];
#pragma unroll
  for(int mt=0;mt<2;mt++)
#pragma unroll
    for(int ksv=0;ksv<2;ksv++){
      const size_t off=(size_t)(b*T_+qr0+mt*16+l16)*2048 + h*128 + (ksv*4+quad)*16;
      qfh[mt][ksv]=*reinterpret_cast<const bf16x8*>(qpi+off);
      qfl[mt][ksv]=*reinterpret_cast<const bf16x8*>(qpi+off+8);
    }

  float mst[2]={-1e30f,-1e30f}, lst[2]={0.f,0.f};
  f32x4 oacc[2][4];
#pragma unroll
  for(int mt=0;mt<2;mt++)
#pragma unroll
    for(int dt=0;dt<4;dt++) oacc[mt][dt]=zero4();

  const int nkt=2*(qt+1);
  for(int kt=0;kt<nkt;kt++){
    const int s0=kt*64;
    __syncthreads();
#pragma unroll
    for(int it=0;it<4;it++){
      const int c=it*256+tid, row=c>>4, j=(c&15)^(row&7);
      gld16(kpi + (size_t)(b*T_+s0+row)*2048 + h*128 + j*8,
            &sK[(it*256+wave*64)*8]);
    }
#pragma unroll
    for(int it=0;it<2;it++){
      const int c=it*256+tid, row=c>>3, j=(c&7)^(row&7);
      gld16(vpT + (size_t)(h*64+row)*8192 + b*T_ + s0 + j*8,
            &sVT[(it*256+wave*64)*8]);
    }
    __syncthreads();

    if(s0<=qr0+31){
      f32x4 sacc[4][2];
#pragma unroll
      for(int st=0;st<4;st++)
#pragma unroll
        for(int mt=0;mt<2;mt++) sacc[st][mt]=zero4();
#pragma unroll
      for(int st=0;st<4;st++)
#pragma unroll
        for(int ksv=0;ksv<2;ksv++){
          const u16* pk=&sK[(st*16+l16)*128];
          const int ch=2*(ksv*4+quad);
          bf16x8 kh=*reinterpret_cast<const bf16x8*>(&pk[((ch  )^sw)*8]);
          bf16x8 kl=*reinterpret_cast<const bf16x8*>(&pk[((ch+1)^sw)*8]);
#pragma unroll
          for(int mt=0;mt<2;mt++){
            sacc[st][mt]=mfma16(kh,qfh[mt][ksv],sacc[st][mt]);
            sacc[st][mt]=mfma16(kl,qfh[mt][ksv],sacc[st][mt]);
            sacc[st][mt]=mfma16(kh,qfl[mt][ksv],sacc[st][mt]);
          }
        }
      const bool needmask=(s0+63>qr0);
      u32 pk_[4][2][2];
#pragma unroll
      for(int mt=0;mt<2;mt++){
        const int qrow=qr0+mt*16+l16;
        float mloc=-1e30f;
        if(needmask){
#pragma unroll
          for(int st=0;st<4;st++)
#pragma unroll
            for(int r=0;r<4;r++){
              float v=sacc[st][mt][r];
              if(s0+st*16+quad*4+r>qrow) v=-1e30f;
              sacc[st][mt][r]=v;
              mloc=fmaxf(mloc,v);
            }
        } else {
#pragma unroll
          for(int st=0;st<4;st++)
#pragma unroll
            for(int r=0;r<4;r++) mloc=fmaxf(mloc,sacc[st][mt][r]);
        }
        mloc=fmaxf(mloc,__shfl_xor(mloc,16,64));
        mloc=fmaxf(mloc,__shfl_xor(mloc,32,64));
        const float nm=fmaxf(mst[mt],mloc);
        const float alpha=exp2f((mst[mt]-nm)*L2E8);
        mst[mt]=nm;
        const float cexp=nm*L2E8;
        float rs=0.f;
#pragma unroll
        for(int st=0;st<4;st++)
#pragma unroll
          for(int r=0;r<4;r++){
            float p=exp2f(__builtin_fmaf(sacc[st][mt][r],L2E8,-cexp));
            sacc[st][mt][r]=p;
            rs+=p;
          }
        lst[mt]=lst[mt]*alpha+rs;
#pragma unroll
        for(int dt=0;dt<4;dt++) oacc[mt][dt]*=alpha;
#pragma unroll
        for(int st=0;st<4;st++){
          pk_[st][mt][0]=pkbf(sacc[st][mt][0],sacc[st][mt][1]);
          pk_[st][mt][1]=pkbf(sacc[st][mt][2],sacc[st][mt][3]);
        }
      }
      const int srcA=(2*(quad&1))*16+l16, srcB=srcA+16;
      const bool hs=(quad>=2);
#pragma unroll
      for(int ksv=0;ksv<2;ksv++){
        bf16x8 b2[2];
#pragma unroll
        for(int mt=0;mt<2;mt++){
          int e0=__shfl((int)pk_[2*ksv  ][mt][0],srcA,64);
          int g0=__shfl((int)pk_[2*ksv+1][mt][0],srcA,64);
          int e1=__shfl((int)pk_[2*ksv  ][mt][1],srcA,64);
          int g1=__shfl((int)pk_[2*ksv+1][mt][1],srcA,64);
          int e2=__shfl((int)pk_[2*ksv  ][mt][0],srcB,64);
          int g2=__shfl((int)pk_[2*ksv+1][mt][0],srcB,64);
          int e3=__shfl((int)pk_[2*ksv  ][mt][1],srcB,64);
          int g3=__shfl((int)pk_[2*ksv+1][mt][1],srcB,64);
          i32x4 bd={ hs?g0:e0, hs?g1:e1, hs?g2:e2, hs?g3:e3 };
          b2[mt]=*reinterpret_cast<bf16x8*>(&bd);
        }
#pragma unroll
        for(int dt=0;dt<4;dt++){
          bf16x8 va=*reinterpret_cast<const bf16x8*>(&sVT[(dt*16+l16)*64 + (((ksv*4+quad)^sw)*8)]);
#pragma unroll
          for(int mt=0;mt<2;mt++)
            oacc[mt][dt]=mfma16(va,b2[mt],oacc[mt][dt]);
        }
      }
    }
  }
#pragma unroll
  for(int mt=0;mt<2;mt++){
    float lt=lst[mt];
    lt+=__shfl_xor(lt,16,64);
    lt+=__shfl_xor(lt,32,64);
    const float inv=1.0f/lt;
    const size_t rb=(size_t)(b*T_+qr0+mt*16+l16)*1024 + h*64;
#pragma unroll
    for(int dt=0;dt<4;dt++){
      u16x4 o4;
#pragma unroll
      for(int r=0;r<4;r++) o4[r]=f2bf(oacc[mt][dt][r]*inv);
      *reinterpret_cast<u16x4*>(yout + rb + dt*16 + quad*4)=o4;
    }
  }
}

// ---------------------------------------------------------------------------
extern "C" void kernel_launch(void* const* d_in, const int* in_sizes, int n_in,
                              void* d_out, int out_size, void* d_ws, size_t ws_size,
                              hipStream_t stream)
{
  const float* q =(const float*)d_in[0];
  // d_in[1] (k) UNUSED: reference quirk computes kp from qp.
  const float* v =(const float*)d_in[2];
  const float* Wq=(const float*)d_in[3];
  const float* Wk=(const float*)d_in[4];
  const float* Wv=(const float*)d_in[5];
  const float* Wp=(const float*)d_in[6];
  const float* bp=(const float*)d_in[7];
  float* out=(float*)d_out;

  const size_t NE=(size_t)M_*E_;          // 8,388,608
  const size_t WE=(size_t)E_*E_;          // 1,048,576
  u16* wsv=(u16*)d_ws;                    // 6NE u16 = 96 MB total
  u16* wq_i =wsv;                         // [0,2WE)   (merged B rows 0..1023)
  u16* wqk_i=wsv+2*WE;                    // [2WE,4WE) (merged B rows 1024..2047)
  u16* wk_i =wsv+4*WE;                    // [4WE,6WE)
  u16* wv_b =wsv+6*WE;                    // [6WE,7WE)
  u16* wp_b =wsv+7*WE;                    // [7WE,8WE)
  u16* vb   =wsv+8*WE;                    // [8WE,8WE+NE); ybf after vp-GEMM
  u16* ybf  =vb;
  u16* qp_i =wsv+8*WE+NE;                 // 2NE
  u16* kp_i =wsv+8*WE+3*NE;               // 2NE  (ends at 8WE+5NE = 6NE exactly)
  u16* wqT_i=kp_i;                        // alias: dead before kp written
  u16* og   =(u16*)d_out;                 // 2NE u16 scratch
  u16* qs_i =og;                          // [0,2NE) until merged GEMM
  u16* vpT  =og;                          // [0,NE) after merged GEMM

  dim3 blk(256);
  cvt_a<<<dim3(NE/2048,2), blk, 0, stream>>>(q, v, qs_i, vb);
  cvt_w<<<dim3(WE/2048,4), blk, 0, stream>>>(Wq, Wk, Wv, Wp, wq_i, wk_i, wv_b, wp_b);
  cvt_t<<<dim3(16,16), blk, 0, stream>>>(Wq, wqT_i);
  // Wqk = Wk @ Wq = Wk @ (Wq^T)^T  (split NT=128, grid 8x8)
  gemm<1,128,0><<<dim3(8,8), blk, 0, stream>>>(wk_i, wqT_i, nullptr, wqk_i, wqk_i, nullptr, 0);
  // [qp | kp] = qs @ [Wq ; Wqk]^T  (split NT=128, grid 16x64)
  gemm<1,128,0><<<dim3(16,64), blk, 0, stream>>>(qs_i, wq_i, nullptr, qp_i, kp_i, nullptr, 0);
  // vpT[e][b*T+t] = Wv @ v^T  (plain NT=64, grid 128x8, ldc=8192)
  gemm<0,64,1><<<dim3(128,8), blk, 0, stream>>>(wv_b, vb, nullptr, vpT, nullptr, nullptr, M_);
  // attention -> ybf (overwrites vb)
  attn<<<dim3(1024), blk, 0, stream>>>(qp_i, kp_i, vpT, ybf);
  // out = ybf @ Wp^T + bp  (plain NT=64, grid 16x64, fp32)
  gemm<0,64,2><<<dim3(16,64), blk, 0, stream>>>(ybf, wp_b, bp, nullptr, nullptr, out, E_);
}